// Round 8
// baseline (1380.980 us; speedup 1.0000x reference)
//
#include <hip/hip_runtime.h>
#include <hip/hip_bf16.h>
#include <math.h>

// Profile-HMM forward (scaled). M=4, B=64, L=512, Q=512, S=26.
//
// Round 8: dual-cluster fat waves. 8 CUs x 512 thr (8 waves x 64 p-cols);
// each WG runs TWO 16-stream clusters of the SAME model m, sharing one
// in-register A copy (breg[4][4] = 128 regs, AGPR-resident per r5/r6).
// Rationale (r7 counters): LDS pipe saturated at ~70% because per-wave MFMA
// A-operand = full 8 KB albuf regardless of p-cols owned; traffic = #waves x
// 8 KB. 8 fat waves halve LDS per unit work; the second cluster restores
// overlap depth (ILP-2 x TLP-2) that killed the 8-wave r5 attempt.
// Carried from r7: LDS-only barrier (no vmcnt drain), one barrier/step,
// lag-2 known gain g_t (exact ll bookkeeping), DPP 4x4 transpose,
// hierarchical S publish (waves 0/1 in parallel).

#define MM 4
#define BB 64
#define LL 512
#define QQ 512
#define SS 26
#define ASTR 528   // albuf row stride bytes (16-mult)

typedef float f32x4 __attribute__((ext_vector_type(4)));
typedef int i32x4 __attribute__((ext_vector_type(4)));
typedef int i32x8 __attribute__((ext_vector_type(8)));

__device__ __forceinline__ float bf2f(unsigned short u) {
    return __uint_as_float(((unsigned)u) << 16);
}
__device__ __forceinline__ unsigned short f2bf(float f) {
    unsigned u = __float_as_uint(f);
    u = u + 0x7FFFu + ((u >> 16) & 1u);   // RNE
    return (unsigned short)(u >> 16);
}
__device__ __forceinline__ unsigned char f2fp8(float x) {
    int r = __builtin_amdgcn_cvt_pk_fp8_f32(x, x, 0, false);
    return (unsigned char)(r & 0xFF);
}
template<int CTRL>
__device__ __forceinline__ float qperm(float x) {
    return __int_as_float(__builtin_amdgcn_update_dpp(
        0, __float_as_int(x), CTRL, 0xF, 0xF, false));
}
// 4x4 f32 transpose across lanes (low 2 lane bits) x regs r[0..3].
__device__ __forceinline__ void tr4(float r[4], bool odd, bool bit1) {
    float t0 = qperm<0xB1>(r[0]), t1 = qperm<0xB1>(r[1]);
    float t2 = qperm<0xB1>(r[2]), t3 = qperm<0xB1>(r[3]);
    float n0 = odd ? t1 : r[0];
    float n1 = odd ? r[1] : t0;
    float n2 = odd ? t3 : r[2];
    float n3 = odd ? r[3] : t2;
    float u0 = qperm<0x4E>(n0), u1 = qperm<0x4E>(n1);
    float u2 = qperm<0x4E>(n2), u3 = qperm<0x4E>(n3);
    r[0] = bit1 ? u2 : n0;
    r[1] = bit1 ? u3 : n1;
    r[2] = bit1 ? n2 : u0;
    r[3] = bit1 ? n3 : u1;
}
__device__ __forceinline__ i32x8 ld32B(const unsigned char* p) {
    i32x4 lo = *(const i32x4*)p;
    i32x4 hi = *(const i32x4*)(p + 16);
    return __builtin_shufflevector(lo, hi, 0, 1, 2, 3, 4, 5, 6, 7);
}
// Barrier that waits only on LDS ops (no vmcnt drain).
// imm 0xC07F: vmcnt=63 (no wait), expcnt=7 (no wait), lgkmcnt=0 (full wait).
__device__ __forceinline__ void barrier_lds() {
    __asm__ __volatile__("" ::: "memory");
    __builtin_amdgcn_s_waitcnt(0xC07F);
    __builtin_amdgcn_s_barrier();
    __asm__ __volatile__("" ::: "memory");
}

// ---------------- preproc (unchanged) ----------------

__global__ void prep_small(const float* __restrict__ il, const float* __restrict__ em,
                           float* __restrict__ pi, float* __restrict__ Bem) {
    int blk = blockIdx.x;
    int m = blk / (QQ + 1);
    int r = blk % (QQ + 1);
    int lane = threadIdx.x;
    if (r < QQ) {
        float x = (lane < SS) ? em[((size_t)m * QQ + r) * SS + lane] : -1e30f;
        float mx = x;
        #pragma unroll
        for (int o = 1; o < 64; o <<= 1) mx = fmaxf(mx, __shfl_xor(mx, o));
        float e = (lane < SS) ? __expf(x - mx) : 0.f;
        float s = e;
        #pragma unroll
        for (int o = 1; o < 64; o <<= 1) s += __shfl_xor(s, o);
        if (lane < SS) Bem[((size_t)m * QQ + r) * SS + lane] = e / s;
    } else {
        float v[8];
        float mx = -1e30f;
        #pragma unroll
        for (int k = 0; k < 8; ++k) { v[k] = il[m * QQ + k * 64 + lane]; mx = fmaxf(mx, v[k]); }
        #pragma unroll
        for (int o = 1; o < 64; o <<= 1) mx = fmaxf(mx, __shfl_xor(mx, o));
        float s = 0.f;
        #pragma unroll
        for (int k = 0; k < 8; ++k) { v[k] = __expf(v[k] - mx); s += v[k]; }
        #pragma unroll
        for (int o = 1; o < 64; o <<= 1) s += __shfl_xor(s, o);
        #pragma unroll
        for (int k = 0; k < 8; ++k) pi[m * QQ + k * 64 + lane] = v[k] / s;
    }
}

__global__ void prep_arow(const float* __restrict__ Al, float* __restrict__ Lrow) {
    int row = blockIdx.x;
    int lane = threadIdx.x;
    const float* p = Al + (size_t)row * QQ;
    float v[8];
    float mx = -1e30f;
    #pragma unroll
    for (int k = 0; k < 8; ++k) { v[k] = p[k * 64 + lane]; mx = fmaxf(mx, v[k]); }
    #pragma unroll
    for (int o = 1; o < 64; o <<= 1) mx = fmaxf(mx, __shfl_xor(mx, o));
    float s = 0.f;
    #pragma unroll
    for (int k = 0; k < 8; ++k) s += __expf(v[k] - mx);
    #pragma unroll
    for (int o = 1; o < 64; o <<= 1) s += __shfl_xor(s, o);
    if (lane == 0) Lrow[row] = mx + __logf(s);
}

// Atq[m][p][q] = fp8(256 * softmax_over_p(A_logits[m][q][:])[p])  (natural q)
__global__ void prep_atq(const float* __restrict__ Al, const float* __restrict__ Lrow,
                         unsigned char* __restrict__ Atq) {
    int bid = blockIdx.x;
    int m = bid >> 3, pb = bid & 7;
    __shared__ unsigned char tile[64][68];
    int l6 = threadIdx.x & 63, g = threadIdx.x >> 6;
    for (int c = 0; c < 8; ++c) {
        #pragma unroll
        for (int r = 0; r < 16; ++r) {
            int ql = g * 16 + r;
            int q = c * 64 + ql;
            float x = Al[((size_t)m * QQ + q) * QQ + pb * 64 + l6];
            tile[ql][l6] = f2fp8(__expf(x - Lrow[m * QQ + q]) * 256.f);
        }
        __syncthreads();
        #pragma unroll
        for (int r = 0; r < 16; ++r) {
            int pr = g * 16 + r;
            Atq[((size_t)m * QQ + pb * 64 + pr) * QQ + c * 64 + l6] = tile[l6][pr];
        }
        __syncthreads();
    }
}

__global__ void prep_e(const float* __restrict__ inp, const float* __restrict__ Bem,
                       unsigned short* __restrict__ E) {
    int bid = blockIdx.x;
    int tc = bid & 7;
    int b = (bid >> 3) & 63;
    int m = bid >> 9;
    int q0 = threadIdx.x;
    float bem0[SS], bem1[SS];
    const float* bp = Bem + (size_t)m * QQ * SS;
    #pragma unroll
    for (int j = 0; j < SS; ++j) bem0[j] = bp[(size_t)q0 * SS + j];
    #pragma unroll
    for (int j = 0; j < SS; ++j) bem1[j] = bp[(size_t)(q0 + 256) * SS + j];
    const float* ip = inp + (((size_t)(m * BB + b)) * LL + tc * 64) * SS;
    for (int lt = 0; lt < 64; ++lt) {
        int t = tc * 64 + lt;
        float a0 = 0.f, a1 = 0.f;
        #pragma unroll
        for (int j = 0; j < SS; ++j) {
            float x = ip[lt * SS + j];
            a0 += x * bem0[j];
            a1 += x * bem1[j];
        }
        size_t o = (((size_t)m * LL + t) * BB + b) * QQ + q0;
        E[o] = f2bf(a0);
        E[o + 256] = f2bf(a1);
    }
}

// ---------------- scan ----------------

__launch_bounds__(512, 2)
__global__ void hmm_scan(const unsigned short* __restrict__ E,
                         const unsigned char* __restrict__ Atq,
                         const float* __restrict__ pi,
                         float* __restrict__ out) {
    const int cu = blockIdx.x;              // 8 WGs
    const int m = cu >> 1;
    const int bg0 = (cu & 1) * 2;           // clusters (m,bg0), (m,bg0+1)
    const int tid = threadIdx.x;
    const int lane = tid & 63;
    const int wv = tid >> 6;                // 0..7, owns p = wv*64 .. +63
    const int n16 = lane & 15;
    const int quad = lane >> 4;
    const int sl = quad * 4 + (lane & 3);   // this lane's stream (post-transpose)
    const int kk = (lane >> 2) & 3;
    const bool odd = (lane & 1) != 0;
    const bool bit1 = (lane & 2) != 0;
    const float LOG256 = 5.545177444479562f;

    __shared__ unsigned char albuf[2][2][16 * ASTR];  // [cl][parity][s][q]
    __shared__ float psl[2][2][16][12];               // [cl][parity][s][wave]
    __shared__ float Sfin[2][2][16];                  // [cl][parity][s]

    // persistent shared-A fragments: this wave's 64 p-cols, full K. 128 regs.
    i32x8 breg[4][4];
    {
        const unsigned char* Ab = Atq + (size_t)m * QQ * QQ;
        #pragma unroll
        for (int h = 0; h < 4; ++h) {
            int p = wv * 64 + h * 16 + n16;
            const unsigned char* rp = Ab + (size_t)p * QQ + quad * 32;
            #pragma unroll
            for (int kc = 0; kc < 4; ++kc)
                breg[h][kc] = ld32B(rp + kc * 128);
        }
    }

    const int wqbase = sl * ASTR + wv * 64 + kk * 4;  // + h*16
    const int arbase = n16 * ASTR + quad * 32;        // + kc*128
    const int qoff = wv * 64 + kk * 4;                // + h*16

    float v[2][4][4];
    float lam[2], gprev[2], ll[2];
    const unsigned short* ept[2];   // -> E[t+1] rows, advanced per step

    // prologue: v_0 = pi * e_0 per cluster; init E pointers at t=1
    #pragma unroll
    for (int cl = 0; cl < 2; ++cl) {
        int b = (bg0 + cl) * 16 + sl;
        const unsigned short* e0p = E + ((size_t)m * LL * BB + b) * QQ;
        ept[cl] = e0p + (size_t)BB * QQ;
        #pragma unroll
        for (int h = 0; h < 4; ++h) {
            int p0 = qoff + h * 16;
            f32x4 pv = *(const f32x4*)(pi + m * QQ + p0);
            ushort4 e0 = *(const ushort4*)(e0p + p0);
            v[cl][h][0] = pv[0] * bf2f(e0.x);
            v[cl][h][1] = pv[1] * bf2f(e0.y);
            v[cl][h][2] = pv[2] * bf2f(e0.z);
            v[cl][h][3] = pv[3] * bf2f(e0.w);
        }
        lam[cl] = 0.5f;
        gprev[cl] = 1.0f;
        ll[cl] = 0.0f;
    }

    auto body = [&](int t, int par) {
        // prefetch e_{t+1} (used at end of this body; ~full step of slack)
        ushort4 et[2][4];
        #pragma unroll
        for (int cl = 0; cl < 2; ++cl) {
            #pragma unroll
            for (int h = 0; h < 4; ++h)
                et[cl][h] = *(const ushort4*)(ept[cl] + qoff + h * 16);
            ept[cl] += (size_t)BB * QQ;
        }

        float g[2];
        #pragma unroll
        for (int cl = 0; cl < 2; ++cl) {
            g[cl] = 128.0f * __builtin_amdgcn_rcpf(lam[cl]);
            unsigned char* ab = &albuf[cl][par][0];
            #pragma unroll
            for (int h = 0; h < 4; ++h) {
                int d = __builtin_amdgcn_cvt_pk_fp8_f32(
                            g[cl] * v[cl][h][0], g[cl] * v[cl][h][1], 0, false);
                d = __builtin_amdgcn_cvt_pk_fp8_f32(
                            g[cl] * v[cl][h][2], g[cl] * v[cl][h][3], d, true);
                *(int*)(ab + wqbase + h * 16) = d;
            }
            float ps = 0.f;
            #pragma unroll
            for (int h = 0; h < 4; ++h)
                ps += (v[cl][h][0] + v[cl][h][1]) + (v[cl][h][2] + v[cl][h][3]);
            ps += __shfl_xor(ps, 4);
            ps += __shfl_xor(ps, 8);
            if ((lane & 12) == 0) psl[cl][par][sl][wv] = ps;
            ll[cl] -= __logf(g[cl]) + LOG256;   // exact bookkeeping
        }

        barrier_lds();

        // waves 0 and 1 publish S_t for their cluster (read next step)
        if (wv < 2 && lane < 16) {
            const f32x4* pr = (const f32x4*)&psl[wv][par][lane][0];
            f32x4 s0 = pr[0], s1 = pr[1];
            Sfin[wv][par][lane] = (s0[0] + s0[1]) + (s0[2] + s0[3])
                                + (s1[0] + s1[1]) + (s1[2] + s1[3]);
        }
        // lag-2 lambda (range control only)
        #pragma unroll
        for (int cl = 0; cl < 2; ++cl) {
            if (t == 0) lam[cl] = 16384.0f;
            else lam[cl] = 16384.0f * g[cl] * gprev[cl] * Sfin[cl][par ^ 1][sl];
            gprev[cl] = g[cl];
        }

        // 32 MX-fp8 MFMA (K=128): 8 independent chains (2 cl x 4 h)
        f32x4 acc[2][4];
        #pragma unroll
        for (int cl = 0; cl < 2; ++cl)
            #pragma unroll
            for (int h = 0; h < 4; ++h) acc[cl][h] = (f32x4){0.f, 0.f, 0.f, 0.f};
        const unsigned char* ar0 = &albuf[0][par][0] + arbase;
        const unsigned char* ar1 = &albuf[1][par][0] + arbase;
        #pragma unroll
        for (int kc = 0; kc < 4; ++kc) {
            i32x8 af0 = ld32B(ar0 + kc * 128);
            i32x8 af1 = ld32B(ar1 + kc * 128);
            #pragma unroll
            for (int h = 0; h < 4; ++h) {
                acc[0][h] = __builtin_amdgcn_mfma_scale_f32_16x16x128_f8f6f4(
                    af0, breg[h][kc], acc[0][h], 0, 0, 0, 0x7F7F7F7F, 0, 0x7F7F7F7F);
                acc[1][h] = __builtin_amdgcn_mfma_scale_f32_16x16x128_f8f6f4(
                    af1, breg[h][kc], acc[1][h], 0, 0, 0, 0x7F7F7F7F, 0, 0x7F7F7F7F);
            }
        }
        // transpose to (one s, 4 consecutive p), multiply e_{t+1}
        #pragma unroll
        for (int cl = 0; cl < 2; ++cl) {
            #pragma unroll
            for (int h = 0; h < 4; ++h) {
                float r[4];
                #pragma unroll
                for (int j = 0; j < 4; ++j) r[j] = acc[cl][h][j];
                tr4(r, odd, bit1);
                v[cl][h][0] = r[0] * bf2f(et[cl][h].x);
                v[cl][h][1] = r[1] * bf2f(et[cl][h].y);
                v[cl][h][2] = r[2] * bf2f(et[cl][h].z);
                v[cl][h][3] = r[3] * bf2f(et[cl][h].w);
            }
        }
    };

    for (int t = 0; t < LL - 2; t += 2) { body(t, 0); body(t + 1, 1); }
    body(LL - 2, 0);   // t = 510 -> v_511

    // epilogue: exact S_511 per cluster
    #pragma unroll
    for (int cl = 0; cl < 2; ++cl) {
        float ps = 0.f;
        #pragma unroll
        for (int h = 0; h < 4; ++h)
            ps += (v[cl][h][0] + v[cl][h][1]) + (v[cl][h][2] + v[cl][h][3]);
        ps += __shfl_xor(ps, 4);
        ps += __shfl_xor(ps, 8);
        if ((lane & 12) == 0) psl[cl][1][sl][wv] = ps;
    }
    __syncthreads();
    if (wv == 0 && (lane & 12) == 0) {
        #pragma unroll
        for (int cl = 0; cl < 2; ++cl) {
            const f32x4* pr = (const f32x4*)&psl[cl][1][sl][0];
            f32x4 s0 = pr[0], s1 = pr[1];
            float S = (s0[0] + s0[1]) + (s0[2] + s0[3])
                    + (s1[0] + s1[1]) + (s1[2] + s1[3]);
            out[m * BB + (bg0 + cl) * 16 + sl] = ll[cl] + __logf(S);
        }
    }
}

// ---------------- host ----------------

extern "C" void kernel_launch(void* const* d_in, const int* in_sizes, int n_in,
                              void* d_out, int out_size, void* d_ws, size_t ws_size,
                              hipStream_t stream) {
    const float* inputs = (const float*)d_in[0];
    const float* A_logits = (const float*)d_in[1];
    const float* init_logits = (const float*)d_in[2];
    const float* em_logits = (const float*)d_in[3];
    float* out = (float*)d_out;

    char* ws = (char*)d_ws;
    size_t off = 0;
    unsigned short* E = (unsigned short*)(ws + off);  off += (size_t)MM * LL * BB * QQ * 2;  // 134 MB
    unsigned char* Atq = (unsigned char*)(ws + off);  off += (size_t)MM * QQ * QQ;           // 1 MB
    float* Bem = (float*)(ws + off);                  off += (size_t)MM * QQ * SS * 4;
    float* pi = (float*)(ws + off);                   off += (size_t)MM * QQ * 4;
    float* Lrow = (float*)(ws + off);                 off += (size_t)MM * QQ * 4;

    if (ws_size < off) {
        (void)hipMemsetAsync(d_out, 0, (size_t)out_size * sizeof(float), stream);
        return;
    }

    prep_small<<<dim3(MM * (QQ + 1)), dim3(64), 0, stream>>>(init_logits, em_logits, pi, Bem);
    prep_arow<<<dim3(MM * QQ), dim3(64), 0, stream>>>(A_logits, Lrow);
    prep_atq<<<dim3(MM * 8), dim3(256), 0, stream>>>(A_logits, Lrow, Atq);
    prep_e<<<dim3(MM * BB * 8), dim3(256), 0, stream>>>(inputs, Bem, E);
    hmm_scan<<<dim3(8), dim3(512), 0, stream>>>(E, Atq, pi, out);
}

// Round 9
// 798.868 us; speedup vs baseline: 1.7287x; 1.7287x over previous
//
#include <hip/hip_runtime.h>
#include <hip/hip_bf16.h>
#include <math.h>

// Profile-HMM forward (scaled). M=4, B=64, L=512, Q=512, S=26.
//
// Round 9 = round 7 (16 clusters x 1024 thr, 16 waves x 32 p-cols, MX-fp8
// K=128, one LDS-only barrier/step, lag-2 gain, DPP transpose) + 3 fixes:
//  1) albuf: 512-B rows + per-row 16B-block rotation (phys_blk=(blk+s)&31).
//     ASTR=528 forced 4-way af-read conflicts (rows ≡ bank 4s, n16 vs n16+8
//     collide); rotation reaches the free 2-way minimum. Addresses t-invariant.
//  2) E layout [m][t][q>>4][b][q&15]: each (wave,h) e-load is one dense
//     contiguous 512-B block (100% coalesced, 1 ushort4/lane).
//  3) MFMA accumulator chains split depth 4 -> 2.

#define MM 4
#define BB 64
#define LL 512
#define QQ 512
#define SS 26

typedef float f32x4 __attribute__((ext_vector_type(4)));
typedef int i32x4 __attribute__((ext_vector_type(4)));
typedef int i32x8 __attribute__((ext_vector_type(8)));

__device__ __forceinline__ float bf2f(unsigned short u) {
    return __uint_as_float(((unsigned)u) << 16);
}
__device__ __forceinline__ unsigned short f2bf(float f) {
    unsigned u = __float_as_uint(f);
    u = u + 0x7FFFu + ((u >> 16) & 1u);   // RNE
    return (unsigned short)(u >> 16);
}
__device__ __forceinline__ unsigned char f2fp8(float x) {
    int r = __builtin_amdgcn_cvt_pk_fp8_f32(x, x, 0, false);
    return (unsigned char)(r & 0xFF);
}
template<int CTRL>
__device__ __forceinline__ float qperm(float x) {
    return __int_as_float(__builtin_amdgcn_update_dpp(
        0, __float_as_int(x), CTRL, 0xF, 0xF, false));
}
// 4x4 f32 transpose across lanes (low 2 lane bits) x regs r[0..3].
__device__ __forceinline__ void tr4(float r[4], bool odd, bool bit1) {
    float t0 = qperm<0xB1>(r[0]), t1 = qperm<0xB1>(r[1]);
    float t2 = qperm<0xB1>(r[2]), t3 = qperm<0xB1>(r[3]);
    float n0 = odd ? t1 : r[0];
    float n1 = odd ? r[1] : t0;
    float n2 = odd ? t3 : r[2];
    float n3 = odd ? r[3] : t2;
    float u0 = qperm<0x4E>(n0), u1 = qperm<0x4E>(n1);
    float u2 = qperm<0x4E>(n2), u3 = qperm<0x4E>(n3);
    r[0] = bit1 ? u2 : n0;
    r[1] = bit1 ? u3 : n1;
    r[2] = bit1 ? n2 : u0;
    r[3] = bit1 ? n3 : u1;
}
__device__ __forceinline__ i32x8 ld32B(const unsigned char* p) {
    i32x4 lo = *(const i32x4*)p;
    i32x4 hi = *(const i32x4*)(p + 16);
    return __builtin_shufflevector(lo, hi, 0, 1, 2, 3, 4, 5, 6, 7);
}
// Barrier that waits only on LDS ops (no vmcnt drain).
// imm 0xC07F: vmcnt=63 (no wait), expcnt=7 (no wait), lgkmcnt=0 (full wait).
__device__ __forceinline__ void barrier_lds() {
    __asm__ __volatile__("" ::: "memory");
    __builtin_amdgcn_s_waitcnt(0xC07F);
    __builtin_amdgcn_s_barrier();
    __asm__ __volatile__("" ::: "memory");
}

// ---------------- preproc ----------------

__global__ void prep_small(const float* __restrict__ il, const float* __restrict__ em,
                           float* __restrict__ pi, float* __restrict__ Bem) {
    int blk = blockIdx.x;
    int m = blk / (QQ + 1);
    int r = blk % (QQ + 1);
    int lane = threadIdx.x;
    if (r < QQ) {
        float x = (lane < SS) ? em[((size_t)m * QQ + r) * SS + lane] : -1e30f;
        float mx = x;
        #pragma unroll
        for (int o = 1; o < 64; o <<= 1) mx = fmaxf(mx, __shfl_xor(mx, o));
        float e = (lane < SS) ? __expf(x - mx) : 0.f;
        float s = e;
        #pragma unroll
        for (int o = 1; o < 64; o <<= 1) s += __shfl_xor(s, o);
        if (lane < SS) Bem[((size_t)m * QQ + r) * SS + lane] = e / s;
    } else {
        float v[8];
        float mx = -1e30f;
        #pragma unroll
        for (int k = 0; k < 8; ++k) { v[k] = il[m * QQ + k * 64 + lane]; mx = fmaxf(mx, v[k]); }
        #pragma unroll
        for (int o = 1; o < 64; o <<= 1) mx = fmaxf(mx, __shfl_xor(mx, o));
        float s = 0.f;
        #pragma unroll
        for (int k = 0; k < 8; ++k) { v[k] = __expf(v[k] - mx); s += v[k]; }
        #pragma unroll
        for (int o = 1; o < 64; o <<= 1) s += __shfl_xor(s, o);
        #pragma unroll
        for (int k = 0; k < 8; ++k) pi[m * QQ + k * 64 + lane] = v[k] / s;
    }
}

__global__ void prep_arow(const float* __restrict__ Al, float* __restrict__ Lrow) {
    int row = blockIdx.x;
    int lane = threadIdx.x;
    const float* p = Al + (size_t)row * QQ;
    float v[8];
    float mx = -1e30f;
    #pragma unroll
    for (int k = 0; k < 8; ++k) { v[k] = p[k * 64 + lane]; mx = fmaxf(mx, v[k]); }
    #pragma unroll
    for (int o = 1; o < 64; o <<= 1) mx = fmaxf(mx, __shfl_xor(mx, o));
    float s = 0.f;
    #pragma unroll
    for (int k = 0; k < 8; ++k) s += __expf(v[k] - mx);
    #pragma unroll
    for (int o = 1; o < 64; o <<= 1) s += __shfl_xor(s, o);
    if (lane == 0) Lrow[row] = mx + __logf(s);
}

// Atq[m][p][q] = fp8(256 * softmax_over_p(A_logits[m][q][:])[p])  (natural q)
__global__ void prep_atq(const float* __restrict__ Al, const float* __restrict__ Lrow,
                         unsigned char* __restrict__ Atq) {
    int bid = blockIdx.x;
    int m = bid >> 3, pb = bid & 7;
    __shared__ unsigned char tile[64][68];
    int l6 = threadIdx.x & 63, g = threadIdx.x >> 6;
    for (int c = 0; c < 8; ++c) {
        #pragma unroll
        for (int r = 0; r < 16; ++r) {
            int ql = g * 16 + r;
            int q = c * 64 + ql;
            float x = Al[((size_t)m * QQ + q) * QQ + pb * 64 + l6];
            tile[ql][l6] = f2fp8(__expf(x - Lrow[m * QQ + q]) * 256.f);
        }
        __syncthreads();
        #pragma unroll
        for (int r = 0; r < 16; ++r) {
            int pr = g * 16 + r;
            Atq[((size_t)m * QQ + pb * 64 + pr) * QQ + c * 64 + l6] = tile[l6][pr];
        }
        __syncthreads();
    }
}

// E5[m][t][q>>4][b][q&15] bf16 = sum_s inputs[m,b,t,s]*Bem[m,q,s].
__global__ void prep_e(const float* __restrict__ inp, const float* __restrict__ Bem,
                       unsigned short* __restrict__ E) {
    int bid = blockIdx.x;
    int tc = bid & 7;
    int b = (bid >> 3) & 63;
    int m = bid >> 9;
    int q0 = threadIdx.x;
    float bem0[SS], bem1[SS];
    const float* bp = Bem + (size_t)m * QQ * SS;
    #pragma unroll
    for (int j = 0; j < SS; ++j) bem0[j] = bp[(size_t)q0 * SS + j];
    #pragma unroll
    for (int j = 0; j < SS; ++j) bem1[j] = bp[(size_t)(q0 + 256) * SS + j];
    const float* ip = inp + (((size_t)(m * BB + b)) * LL + tc * 64) * SS;
    for (int lt = 0; lt < 64; ++lt) {
        int t = tc * 64 + lt;
        float a0 = 0.f, a1 = 0.f;
        #pragma unroll
        for (int j = 0; j < SS; ++j) {
            float x = ip[lt * SS + j];
            a0 += x * bem0[j];
            a1 += x * bem1[j];
        }
        size_t base = ((size_t)(m * LL + t)) * 32768;  // 32*64*16
        E[base + ((size_t)(q0 >> 4) * 64 + b) * 16 + (q0 & 15)] = f2bf(a0);
        E[base + ((size_t)((q0 + 256) >> 4) * 64 + b) * 16 + (q0 & 15)] = f2bf(a1);
    }
}

// ---------------- scan ----------------

__launch_bounds__(1024, 4)
__global__ void hmm_scan(const unsigned short* __restrict__ E,
                         const unsigned char* __restrict__ Atq,
                         const float* __restrict__ pi,
                         float* __restrict__ out) {
    const int c = blockIdx.x;               // 16 clusters
    const int m = c >> 2, bg = c & 3;
    const int tid = threadIdx.x;
    const int lane = tid & 63;
    const int wv = tid >> 6;                // 0..15, owns p = wv*32 .. wv*32+31
    const int n16 = lane & 15;
    const int quad = lane >> 4;
    const int sl = quad * 4 + (lane & 3);   // this lane's stream (post-transpose)
    const int kk = (lane >> 2) & 3;
    const bool odd = (lane & 1) != 0;
    const bool bit1 = (lane & 2) != 0;
    const float LOG256 = 5.545177444479562f;

    // albuf: [parity][s:16][32 x 16B blocks], phys block = (logical + s) & 31
    __shared__ __align__(16) unsigned char albuf[2][16 * 512];
    __shared__ float psl[2][16][20];
    __shared__ float Sfin[2][16];

    // persistent B-fragments: this wave's 32 p-columns of fp8(256*A[m]).
    i32x8 breg[2][4];
    {
        const unsigned char* Ab = Atq + (size_t)m * QQ * QQ;
        #pragma unroll
        for (int h = 0; h < 2; ++h) {
            int p = wv * 32 + h * 16 + n16;
            const unsigned char* rp = Ab + (size_t)p * QQ + quad * 32;
            #pragma unroll
            for (int kc = 0; kc < 4; ++kc)
                breg[h][kc] = ld32B(rp + kc * 128);
        }
    }

    // t-invariant LDS addresses (block-rotated layout)
    int wq[2];      // write: row sl, logical block wv*2+h, inner kk*4
    #pragma unroll
    for (int h = 0; h < 2; ++h)
        wq[h] = sl * 512 + (((wv * 2 + h + sl) & 31) << 4) + kk * 4;
    int aoff[4][2]; // read: row n16, logical block kc*8+quad*2+half
    #pragma unroll
    for (int kc = 0; kc < 4; ++kc)
        #pragma unroll
        for (int hf = 0; hf < 2; ++hf)
            aoff[kc][hf] = n16 * 512 + (((kc * 8 + quad * 2 + hf + n16) & 31) << 4);
    // t-invariant e-load offset per h (dense E5 block per (wave,h))
    int eoff[2];
    #pragma unroll
    for (int h = 0; h < 2; ++h)
        eoff[h] = (wv * 2 + h) * 1024 + (bg * 16 + sl) * 16 + kk * 4;

    float v[2][4];
    ushort4 ea[2], eb[2];

    // prologue: prefetch e_1 -> ea ; v_0 = pi * e_0
    {
        const unsigned short* E1 = E + ((size_t)m * LL + 1) * 32768;
        const unsigned short* E0 = E + ((size_t)m * LL) * 32768;
        #pragma unroll
        for (int h = 0; h < 2; ++h) ea[h] = *(const ushort4*)(E1 + eoff[h]);
        #pragma unroll
        for (int h = 0; h < 2; ++h) {
            int p0 = wv * 32 + h * 16 + kk * 4;
            f32x4 pv = *(const f32x4*)(pi + m * QQ + p0);
            ushort4 e0 = *(const ushort4*)(E0 + eoff[h]);
            v[h][0] = pv[0] * bf2f(e0.x);
            v[h][1] = pv[1] * bf2f(e0.y);
            v[h][2] = pv[2] * bf2f(e0.z);
            v[h][3] = pv[3] * bf2f(e0.w);
        }
    }

    float lam = 0.5f;
    float gprev = 1.0f;
    float ll = 0.0f;

    auto body = [&](int t, ushort4 (&ecur)[2], ushort4 (&enxt)[2]) {
        const int par = t & 1;
        // prefetch e_{t+2} (consumed next iteration; never force-drained)
        int tp = t + 2; if (tp > LL - 1) tp = LL - 1;
        const unsigned short* Ep = E + ((size_t)m * LL + tp) * 32768;
        #pragma unroll
        for (int h = 0; h < 2; ++h) enxt[h] = *(const ushort4*)(Ep + eoff[h]);

        float g = 128.0f * __builtin_amdgcn_rcpf(lam);
        // alpha-hat_t = fp8(g * v_t), packed 4 bytes -> one b32 per h
        unsigned char* ab = &albuf[par][0];
        #pragma unroll
        for (int h = 0; h < 2; ++h) {
            int d = __builtin_amdgcn_cvt_pk_fp8_f32(g * v[h][0], g * v[h][1], 0, false);
            d = __builtin_amdgcn_cvt_pk_fp8_f32(g * v[h][2], g * v[h][3], d, true);
            *(int*)(ab + wq[h]) = d;
        }
        // per-wave partial sum for S_t (own stream sl)
        float ps = (v[0][0] + v[0][1]) + (v[0][2] + v[0][3])
                 + (v[1][0] + v[1][1]) + (v[1][2] + v[1][3]);
        ps += __shfl_xor(ps, 4);
        ps += __shfl_xor(ps, 8);
        if ((lane & 12) == 0) psl[par][sl][wv] = ps;

        ll -= __logf(g) + LOG256;   // exact: ll = log S_L - sum log(256 g_t)

        barrier_lds();              // LDS-only wait; no vmcnt drain

        // wave 0 publishes S_t for step t+1's consumers
        if (wv == 0 && lane < 16) {
            const f32x4* pr = (const f32x4*)&psl[par][lane][0];
            f32x4 s0 = pr[0], s1 = pr[1], s2 = pr[2], s3 = pr[3];
            f32x4 ss = (s0 + s1) + (s2 + s3);
            Sfin[par][lane] = (ss[0] + ss[1]) + (ss[2] + ss[3]);
        }
        // lag-2 lambda update (range control only; ll bookkeeping stays exact)
        if (t == 0) {
            lam = 16384.0f;
        } else {
            float Sp = Sfin[par ^ 1][sl];   // S_{t-1}, published during body(t-1)
            lam = 16384.0f * g * gprev * Sp;
        }
        gprev = g;

        // r = alpha-hat @ A-hat : 8 MX-fp8 MFMA (K=128), 4 chains (depth 2)
        f32x4 acc[2][2];
        acc[0][0] = (f32x4){0.f,0.f,0.f,0.f}; acc[0][1] = (f32x4){0.f,0.f,0.f,0.f};
        acc[1][0] = (f32x4){0.f,0.f,0.f,0.f}; acc[1][1] = (f32x4){0.f,0.f,0.f,0.f};
        #pragma unroll
        for (int kc = 0; kc < 4; ++kc) {
            i32x4 lo = *(const i32x4*)(ab + aoff[kc][0]);
            i32x4 hi = *(const i32x4*)(ab + aoff[kc][1]);
            i32x8 af = __builtin_shufflevector(lo, hi, 0, 1, 2, 3, 4, 5, 6, 7);
            #pragma unroll
            for (int h = 0; h < 2; ++h)
                acc[h][kc >> 1] = __builtin_amdgcn_mfma_scale_f32_16x16x128_f8f6f4(
                    af, breg[h][kc], acc[h][kc >> 1], 0, 0,
                    0, 0x7F7F7F7F, 0, 0x7F7F7F7F);   // unit e8m0 scales
        }
        // transpose to (one s, 4 consecutive p) ownership, then e-multiply
        #pragma unroll
        for (int h = 0; h < 2; ++h) {
            float r[4];
            #pragma unroll
            for (int j = 0; j < 4; ++j) r[j] = acc[h][0][j] + acc[h][1][j];
            tr4(r, odd, bit1);
            v[h][0] = r[0] * bf2f(ecur[h].x);
            v[h][1] = r[1] * bf2f(ecur[h].y);
            v[h][2] = r[2] * bf2f(ecur[h].z);
            v[h][3] = r[3] * bf2f(ecur[h].w);
        }
    };

    for (int t = 0; t < LL - 2; t += 2) { body(t, ea, eb); body(t + 1, eb, ea); }
    body(LL - 2, ea, eb);

    // epilogue: exact S_511
    {
        float ps = (v[0][0] + v[0][1]) + (v[0][2] + v[0][3])
                 + (v[1][0] + v[1][1]) + (v[1][2] + v[1][3]);
        ps += __shfl_xor(ps, 4);
        ps += __shfl_xor(ps, 8);
        if ((lane & 12) == 0) psl[1][sl][wv] = ps;
        __syncthreads();
        const f32x4* pr = (const f32x4*)&psl[1][sl][0];
        f32x4 s0 = pr[0], s1 = pr[1], s2 = pr[2], s3 = pr[3];
        f32x4 ss = (s0 + s1) + (s2 + s3);
        float S = (ss[0] + ss[1]) + (ss[2] + ss[3]);
        ll += __logf(S);
        if (wv == 0 && (lane & 12) == 0)
            out[m * BB + bg * 16 + sl] = ll;
    }
}

// ---------------- host ----------------

extern "C" void kernel_launch(void* const* d_in, const int* in_sizes, int n_in,
                              void* d_out, int out_size, void* d_ws, size_t ws_size,
                              hipStream_t stream) {
    const float* inputs = (const float*)d_in[0];
    const float* A_logits = (const float*)d_in[1];
    const float* init_logits = (const float*)d_in[2];
    const float* em_logits = (const float*)d_in[3];
    float* out = (float*)d_out;

    char* ws = (char*)d_ws;
    size_t off = 0;
    unsigned short* E = (unsigned short*)(ws + off);  off += (size_t)MM * LL * BB * QQ * 2;  // 134 MB
    unsigned char* Atq = (unsigned char*)(ws + off);  off += (size_t)MM * QQ * QQ;           // 1 MB
    float* Bem = (float*)(ws + off);                  off += (size_t)MM * QQ * SS * 4;
    float* pi = (float*)(ws + off);                   off += (size_t)MM * QQ * 4;
    float* Lrow = (float*)(ws + off);                 off += (size_t)MM * QQ * 4;

    if (ws_size < off) {
        (void)hipMemsetAsync(d_out, 0, (size_t)out_size * sizeof(float), stream);
        return;
    }

    prep_small<<<dim3(MM * (QQ + 1)), dim3(64), 0, stream>>>(init_logits, em_logits, pi, Bem);
    prep_arow<<<dim3(MM * QQ), dim3(64), 0, stream>>>(A_logits, Lrow);
    prep_atq<<<dim3(MM * 8), dim3(256), 0, stream>>>(A_logits, Lrow, Atq);
    prep_e<<<dim3(MM * BB * 8), dim3(256), 0, stream>>>(inputs, Bem, E);
    hmm_scan<<<dim3(16), dim3(1024), 0, stream>>>(E, Atq, pi, out);
}